// Round 3
// baseline (839.952 us; speedup 1.0000x reference)
//
#include <hip/hip_runtime.h>

// LightGCN propagation on MI355X — R11: single-pass k_sort via precomputed
// global row histogram.
//
// R10 post-mortem: k_part fix worked (663->628, k_part out of top-5). SpMM is
// now ~350us of the 628 and runs at ~6.9TB/s effective (3.58 HBM + L2/LLC) —
// near its mixed roofline. Remaining slack: prep chain ~260us, structurally
// k_sort's double pass over pairs1 (48MB re-read + 6M LDS atomics + scan)
// just to build the per-bucket row histogram.
//
// R11: k_rhist (grid-stride, 6M global atomicAdd into 600KB L2-resident rcnt;
// proven cheap in R9) -> k_bsum/k_bscan/k_rscan (tiny scans) produce row_ptr
// AND bucket offsets before k_part. k_sort becomes single-pass: LDS cursors
// init from row_ptr, one read of pairs1, scatter to pairs2. k_bhist deleted.
// rcnt aliases the pairs2 region (dead until k_sort) -> NEEDED unchanged.
//
// Inputs: [2] adj_src (6M int), [3] adj_dst (6M int), [4] adj_vals (6M f32),
//         [5] user_emb (100000x64 f32), [6] item_emb (50000x64 f32).
// Output: [150000x64] f32 = (e0+e1+e2+e3)/4.

#define NUM_USERS 100000
#define NUM_ITEMS 50000
#define N_NODES   150000
#define EMB       64
#define N_EDGES   6000000

#define ROWS_PER_B 256
#define NBUCKETS   586                        // ceil(150000/256)
#define NROWS_PAD  (NBUCKETS * ROWS_PER_B)    // 150016
#define PART_BLOCKS 512
#define CHUNK ((N_EDGES + PART_BLOCKS - 1) / PART_BLOCKS)   // 11719

constexpr int NODE_F4 = N_NODES * EMB / 4;   // 2,400,000
constexpr int USER_F4 = NUM_USERS * EMB / 4; // 1,600,000

typedef float f4v __attribute__((ext_vector_type(4)));   // 16B clang vector

__device__ __forceinline__ float bf2f(unsigned short u) {
    union { unsigned int i; float f; } x; x.i = ((unsigned int)u) << 16; return x.f;
}
__device__ __forceinline__ unsigned short f2bf(float f) {
    union { float f; unsigned int i; } x; x.f = f;
    unsigned int b = x.i;
    return (unsigned short)((b + 0x7FFFu + ((b >> 16) & 1u)) >> 16);  // RNE
}

// ---------------- phase 0: row histogram + two-level scan ----------------

__global__ void k_zero(int* __restrict__ p, int n) {
    int i = blockIdx.x * blockDim.x + threadIdx.x;
    if (i < n) p[i] = 0;
}

// 6M global atomics into 600KB L2-resident table (R9: this pattern is cheap).
__global__ __launch_bounds__(256) void k_rhist(const int* __restrict__ dst,
                                               int* __restrict__ rcnt) {
    int e0 = blockIdx.x * CHUNK;
    int e1 = min(e0 + CHUNK, N_EDGES);
    int e = e0 + threadIdx.x;
    for (; e + 7 * 256 < e1; e += 8 * 256) {
        int d_[8];
#pragma unroll
        for (int j = 0; j < 8; ++j)
            d_[j] = __builtin_nontemporal_load(dst + e + j * 256);
#pragma unroll
        for (int j = 0; j < 8; ++j) atomicAdd(&rcnt[d_[j]], 1);
    }
    for (; e < e1; e += 256)
        atomicAdd(&rcnt[__builtin_nontemporal_load(dst + e)], 1);
}

// per-bucket (256-row block) sums of rcnt (overwrites gcnt, no zeroing needed)
__global__ __launch_bounds__(256) void k_bsum(const int* __restrict__ rcnt,
                                              int* __restrict__ gcnt) {
    __shared__ int s[256];
    int b = blockIdx.x, t = threadIdx.x;
    s[t] = rcnt[b * 256 + t];
    __syncthreads();
    for (int off = 128; off > 0; off >>= 1) {
        if (t < off) s[t] += s[t + off];
        __syncthreads();
    }
    if (t == 0) gcnt[b] = s[0];
}

__global__ void k_bscan(const int* __restrict__ gcnt, int* __restrict__ boff,
                        int* __restrict__ gcur) {
    __shared__ int s[1024];
    int t = threadIdx.x;
    int x = (t < NBUCKETS) ? gcnt[t] : 0;
    s[t] = x;
    __syncthreads();
    for (int off = 1; off < 1024; off <<= 1) {
        int v = (t >= off) ? s[t - off] : 0;
        __syncthreads();
        s[t] += v;
        __syncthreads();
    }
    if (t < NBUCKETS) { int ex = s[t] - x; boff[t] = ex; gcur[t] = ex; }
    if (t == 0) boff[NBUCKETS] = N_EDGES;
}

// per-row exclusive scan within bucket + bucket offset -> row_ptr
__global__ __launch_bounds__(256) void k_rscan(const int* __restrict__ rcnt,
                                               const int* __restrict__ boff,
                                               int* __restrict__ row_ptr) {
    __shared__ int s[256];
    int b = blockIdx.x, t = threadIdx.x;
    int x = rcnt[b * 256 + t];
    s[t] = x;
    __syncthreads();
    for (int off = 1; off < 256; off <<= 1) {
        int v = (t >= off) ? s[t - off] : 0;
        __syncthreads();
        s[t] += v;
        __syncthreads();
    }
    row_ptr[b * 256 + t] = boff[b] + s[t] - x;
    if (b == NBUCKETS - 1 && t == 255) row_ptr[NROWS_PAD] = N_EDGES;
}

// ---------------- phase 1: bucket partition ----------------
// entry: x = src | (dstLocal<<18), y = val bits

__global__ __launch_bounds__(256) void k_part(const int* __restrict__ src,
                                              const int* __restrict__ dst,
                                              const float* __restrict__ val,
                                              int* __restrict__ gcur,
                                              int2* __restrict__ pairs) {
    __shared__ int cnt[NBUCKETS];
    __shared__ int base[NBUCKETS];
    int t = threadIdx.x;
    for (int i = t; i < NBUCKETS; i += 256) cnt[i] = 0;
    __syncthreads();
    int e0 = blockIdx.x * CHUNK;
    int e1 = min(e0 + CHUNK, N_EDGES);
    {
        int e = e0 + t;
        for (; e + 7 * 256 < e1; e += 8 * 256) {
            int b_[8];
#pragma unroll
            for (int j = 0; j < 8; ++j)
                b_[j] = __builtin_nontemporal_load(dst + e + j * 256) >> 8;
#pragma unroll
            for (int j = 0; j < 8; ++j) atomicAdd(&cnt[b_[j]], 1);
        }
        for (; e < e1; e += 256)
            atomicAdd(&cnt[__builtin_nontemporal_load(dst + e) >> 8], 1);
    }
    __syncthreads();
    for (int i = t; i < NBUCKETS; i += 256) {
        int c = cnt[i];
        base[i] = c ? atomicAdd(&gcur[i], c) : 0;
        cnt[i] = 0;
    }
    __syncthreads();
    {
        int e = e0 + t;
        for (; e + 7 * 256 < e1; e += 8 * 256) {
            int d_[8], s_[8];
            float v_[8];
#pragma unroll
            for (int j = 0; j < 8; ++j)
                d_[j] = __builtin_nontemporal_load(dst + e + j * 256);
#pragma unroll
            for (int j = 0; j < 8; ++j)
                s_[j] = __builtin_nontemporal_load(src + e + j * 256);
#pragma unroll
            for (int j = 0; j < 8; ++j)
                v_[j] = __builtin_nontemporal_load(val + e + j * 256);
#pragma unroll
            for (int j = 0; j < 8; ++j) {
                int b_ = d_[j] >> 8;
                int o = atomicAdd(&cnt[b_], 1);
                pairs[base[b_] + o] = make_int2(s_[j] | ((d_[j] & 255) << 18),
                                                __float_as_int(v_[j]));
            }
        }
        for (; e < e1; e += 256) {
            int d0 = __builtin_nontemporal_load(dst + e);
            int s0 = __builtin_nontemporal_load(src + e);
            float v0 = __builtin_nontemporal_load(val + e);
            int b_ = d0 >> 8;
            int o0 = atomicAdd(&cnt[b_], 1);
            pairs[base[b_] + o0] = make_int2(s0 | ((d0 & 255) << 18),
                                             __float_as_int(v0));
        }
    }
}

// ---------------- phase 2: single-pass placement (cursors from row_ptr) ----------------

__global__ __launch_bounds__(512) void k_sort(const int* __restrict__ boff,
                                              const int* __restrict__ row_ptr,
                                              const int2* __restrict__ pairs1,
                                              int2* __restrict__ pairs2) {
    __shared__ int cnt[ROWS_PER_B];    // global-position cursors
    int b = blockIdx.x;
    int t = threadIdx.x;
    if (t < ROWS_PER_B) cnt[t] = row_ptr[b * ROWS_PER_B + t];
    __syncthreads();
    int beg = boff[b], end = boff[b + 1];
    const long* p1l = (const long*)pairs1;
    int e = beg + t;
    for (; e + 7 * 512 < end; e += 8 * 512) {
        long q[8];
#pragma unroll
        for (int j = 0; j < 8; ++j)
            q[j] = __builtin_nontemporal_load(p1l + e + j * 512);   // only read: NT
#pragma unroll
        for (int j = 0; j < 8; ++j) {
            int x0 = (int)q[j], y0 = (int)(q[j] >> 32);
            int pos = atomicAdd(&cnt[((unsigned)x0) >> 18], 1);
            pairs2[pos] = make_int2(x0 & 0x3FFFF, y0);
        }
    }
    for (; e < end; e += 512) {
        long q0 = __builtin_nontemporal_load(p1l + e);
        int x0 = (int)q0, y0 = (int)(q0 >> 32);
        int pos = atomicAdd(&cnt[((unsigned)x0) >> 18], 1);
        pairs2[pos] = make_int2(x0 & 0x3FFFF, y0);
    }
}

// ---------------- phase 3: propagation ----------------

__global__ void k_init(const f4v* __restrict__ ue, const f4v* __restrict__ ie,
                       ushort4* __restrict__ e0b, f4v* __restrict__ acc) {
    int i = blockIdx.x * blockDim.x + threadIdx.x;
    if (i >= NODE_F4) return;
    f4v v = (i < USER_F4) ? __builtin_nontemporal_load(ue + i)
                          : __builtin_nontemporal_load(ie + i - USER_F4);
    __builtin_nontemporal_store(v, acc + i);     // re-read only in the final layer
    e0b[i] = make_ushort4(f2bf(v.x), f2bf(v.y), f2bf(v.z), f2bf(v.w));
}

// 16 lanes/row; lane owns 4 channels (8B ushort4 gather). Unroll-8: 8 pair
// loads issued, then 8 independent gathers in flight. Layers 0/1: nxt only.
__global__ __launch_bounds__(256) void k_spmm(const int* __restrict__ row_ptr,
                                              const long* __restrict__ pairs,
                                              const ushort4* __restrict__ cur,
                                              ushort4* __restrict__ nxt) {
    int tid = blockIdx.x * blockDim.x + threadIdx.x;
    int row = tid >> 4;
    if (row >= N_NODES) return;
    int c = tid & 15;
    int beg = row_ptr[row];
    int end = row_ptr[row + 1];
    float4 r = make_float4(0.f, 0.f, 0.f, 0.f);
    int k = beg;
    for (; k + 7 < end; k += 8) {
        long p[8];
        ushort4 g[8];
#pragma unroll
        for (int j = 0; j < 8; ++j) p[j] = pairs[k + j];
#pragma unroll
        for (int j = 0; j < 8; ++j) g[j] = cur[(long)(int)(p[j] & 0x3FFFF) * 16 + c];
#pragma unroll
        for (int j = 0; j < 8; ++j) {
            float v = __int_as_float((int)(p[j] >> 32));
            r.x += v * bf2f(g[j].x);
            r.y += v * bf2f(g[j].y);
            r.z += v * bf2f(g[j].z);
            r.w += v * bf2f(g[j].w);
        }
    }
    for (; k < end; ++k) {
        long p0 = pairs[k];
        ushort4 g0 = cur[(long)(int)(p0 & 0x3FFFF) * 16 + c];
        float v0 = __int_as_float((int)(p0 >> 32));
        r.x += v0 * bf2f(g0.x);
        r.y += v0 * bf2f(g0.y);
        r.z += v0 * bf2f(g0.z);
        r.w += v0 * bf2f(g0.w);
    }
    nxt[(long)row * 16 + c] = make_ushort4(f2bf(r.x), f2bf(r.y), f2bf(r.z), f2bf(r.w));
}

// Final layer: r = SpMM(e2); acc = (acc + e1 + e2 + r) * 0.25
__global__ __launch_bounds__(256) void k_spmm_fin(const int* __restrict__ row_ptr,
                                                  const long* __restrict__ pairs,
                                                  const ushort4* __restrict__ cur,  // e2b
                                                  const ushort4* __restrict__ e1b,
                                                  float4* __restrict__ acc) {
    int tid = blockIdx.x * blockDim.x + threadIdx.x;
    int row = tid >> 4;
    if (row >= N_NODES) return;
    int c = tid & 15;
    int beg = row_ptr[row];
    int end = row_ptr[row + 1];
    float4 r = make_float4(0.f, 0.f, 0.f, 0.f);
    int k = beg;
    for (; k + 7 < end; k += 8) {
        long p[8];
        ushort4 g[8];
#pragma unroll
        for (int j = 0; j < 8; ++j) p[j] = pairs[k + j];
#pragma unroll
        for (int j = 0; j < 8; ++j) g[j] = cur[(long)(int)(p[j] & 0x3FFFF) * 16 + c];
#pragma unroll
        for (int j = 0; j < 8; ++j) {
            float v = __int_as_float((int)(p[j] >> 32));
            r.x += v * bf2f(g[j].x);
            r.y += v * bf2f(g[j].y);
            r.z += v * bf2f(g[j].z);
            r.w += v * bf2f(g[j].w);
        }
    }
    for (; k < end; ++k) {
        long p0 = pairs[k];
        ushort4 g0 = cur[(long)(int)(p0 & 0x3FFFF) * 16 + c];
        float v0 = __int_as_float((int)(p0 >> 32));
        r.x += v0 * bf2f(g0.x);
        r.y += v0 * bf2f(g0.y);
        r.z += v0 * bf2f(g0.z);
        r.w += v0 * bf2f(g0.w);
    }
    long o = (long)row * 16 + c;
    ushort4 e1 = e1b[o];
    ushort4 e2 = cur[o];
    float4 a = acc[o];
    a.x = (a.x + bf2f(e1.x) + bf2f(e2.x) + r.x) * 0.25f;
    a.y = (a.y + bf2f(e1.y) + bf2f(e2.y) + r.y) * 0.25f;
    a.z = (a.z + bf2f(e1.z) + bf2f(e2.z) + r.z) * 0.25f;
    a.w = (a.w + bf2f(e1.w) + bf2f(e2.w) + r.w) * 0.25f;
    acc[o] = a;
}

// ---------------- R0 fallback (atomic scatter) for small ws ----------------

__global__ void lgcn_init(const float4* __restrict__ user_emb,
                          const float4* __restrict__ item_emb,
                          float4* __restrict__ cur, float4* __restrict__ nxt,
                          float4* __restrict__ acc) {
    int i = blockIdx.x * blockDim.x + threadIdx.x;
    if (i >= NODE_F4) return;
    float4 v = (i < USER_F4) ? user_emb[i] : item_emb[i - USER_F4];
    cur[i] = v; acc[i] = v; nxt[i] = make_float4(0.f, 0.f, 0.f, 0.f);
}

__global__ void lgcn_scatter(const int* __restrict__ src, const int* __restrict__ dst,
                             const float* __restrict__ val,
                             const float4* __restrict__ cur, float* __restrict__ nxt) {
    int tid = blockIdx.x * blockDim.x + threadIdx.x;
    int e = tid >> 4;
    if (e >= N_EDGES) return;
    int c = tid & 15;
    int s = src[e]; int d = dst[e]; float v = val[e];
    float4 m = cur[(long)s * 16 + c];
    float* p = nxt + (long)d * 64 + c * 4;
    unsafeAtomicAdd(p + 0, v * m.x);
    unsafeAtomicAdd(p + 1, v * m.y);
    unsafeAtomicAdd(p + 2, v * m.z);
    unsafeAtomicAdd(p + 3, v * m.w);
}

__global__ void lgcn_add_zero(float4* __restrict__ acc, const float4* __restrict__ nxt,
                              float4* __restrict__ other) {
    int i = blockIdx.x * blockDim.x + threadIdx.x;
    if (i >= NODE_F4) return;
    float4 a = acc[i]; float4 n = nxt[i];
    a.x += n.x; a.y += n.y; a.z += n.z; a.w += n.w;
    acc[i] = a;
    other[i] = make_float4(0.f, 0.f, 0.f, 0.f);
}

__global__ void lgcn_final(float4* __restrict__ acc, const float4* __restrict__ nxt) {
    int i = blockIdx.x * blockDim.x + threadIdx.x;
    if (i >= NODE_F4) return;
    float4 a = acc[i]; float4 n = nxt[i];
    a.x = (a.x + n.x) * 0.25f; a.y = (a.y + n.y) * 0.25f;
    a.z = (a.z + n.z) * 0.25f; a.w = (a.w + n.w) * 0.25f;
    acc[i] = a;
}

// ---------------- launch ----------------

extern "C" void kernel_launch(void* const* d_in, const int* in_sizes, int n_in,
                              void* d_out, int out_size, void* d_ws, size_t ws_size,
                              hipStream_t stream) {
    const int*    adj_src  = (const int*)d_in[2];
    const int*    adj_dst  = (const int*)d_in[3];
    const float*  adj_vals = (const float*)d_in[4];
    float* acc = (float*)d_out;

    const int BLK = 256;
    const int grid_node  = (NODE_F4 + BLK - 1) / BLK;        // 9375
    const int grid_row16 = (N_NODES * 16 + BLK - 1) / BLK;   // 9375

    // workspace layout (bytes):
    //   [0, 48MB)      pairs2; [0, 600KB) transiently rcnt (dead before k_sort)
    //   [48, 96MB)     pairs1; after k_sort reused: e0b (19.2) + e1b (19.2)
    //   [96, 115.2MB)  e2b
    //   [115.2MB, ...) row_ptr (150017 ints), gcnt, boff, gcur
    const size_t SZ_PAIRS = (size_t)N_EDGES * 8;             // 48,000,000
    const size_t SZ_BF    = (size_t)N_NODES * EMB * 2;       // 19,200,000
    const size_t SZ_RP    = 600320;                          // 150017 ints, padded
    const size_t SZ_B     = 4096;
    const size_t NEEDED   = 2 * SZ_PAIRS + SZ_BF + SZ_RP + 3 * SZ_B;  // ~115.8 MB

    if (ws_size >= NEEDED) {
        char* w = (char*)d_ws;
        int2*    pairs2 = (int2*)(w);
        int*     rcnt   = (int*)(w);                          // aliases pairs2 head
        int2*    pairs1 = (int2*)(w + SZ_PAIRS);
        ushort4* e0b    = (ushort4*)(w + SZ_PAIRS);           // aliases pairs1
        ushort4* e1b    = (ushort4*)(w + SZ_PAIRS + SZ_BF);   // aliases pairs1
        ushort4* e2b    = (ushort4*)(w + 2 * SZ_PAIRS);
        int*  row_ptr= (int*)(w + 2 * SZ_PAIRS + SZ_BF);
        int*  gcnt   = (int*)(w + 2 * SZ_PAIRS + SZ_BF + SZ_RP);
        int*  boff   = (int*)(w + 2 * SZ_PAIRS + SZ_BF + SZ_RP + SZ_B);
        int*  gcur   = (int*)(w + 2 * SZ_PAIRS + SZ_BF + SZ_RP + 2 * SZ_B);

        // phase 0: row histogram -> row_ptr + bucket offsets
        k_zero<<<(NROWS_PAD + BLK - 1) / BLK, BLK, 0, stream>>>(rcnt, NROWS_PAD);
        k_rhist<<<PART_BLOCKS, BLK, 0, stream>>>(adj_dst, rcnt);
        k_bsum<<<NBUCKETS, BLK, 0, stream>>>(rcnt, gcnt);
        k_bscan<<<1, 1024, 0, stream>>>(gcnt, boff, gcur);
        k_rscan<<<NBUCKETS, BLK, 0, stream>>>(rcnt, boff, row_ptr);

        // phase 1: bucket partition (rcnt dead from here; pairs2 region free)
        k_part<<<PART_BLOCKS, BLK, 0, stream>>>(adj_src, adj_dst, adj_vals, gcur, pairs1);

        // phase 2: single-pass row placement -> pairs2
        k_sort<<<NBUCKETS, 512, 0, stream>>>(boff, row_ptr, pairs1, pairs2);

        // phase 3: propagation (pairs1 region reused for e0b/e1b)
        k_init<<<grid_node, BLK, 0, stream>>>((const f4v*)d_in[5], (const f4v*)d_in[6],
                                              e0b, (f4v*)acc);
        k_spmm<<<grid_row16, BLK, 0, stream>>>(row_ptr, (const long*)pairs2, e0b, e1b);
        k_spmm<<<grid_row16, BLK, 0, stream>>>(row_ptr, (const long*)pairs2, e1b, e2b);
        k_spmm_fin<<<grid_row16, BLK, 0, stream>>>(row_ptr, (const long*)pairs2, e2b,
                                                   e1b, (float4*)acc);
    } else {
        // R0 fallback: atomic scatter
        const float4* user_emb = (const float4*)d_in[5];
        const float4* item_emb = (const float4*)d_in[6];
        float* ws0 = (float*)d_ws;
        float* ws1 = ws0 + (size_t)N_NODES * EMB;
        lgcn_init<<<grid_node, BLK, 0, stream>>>(user_emb, item_emb,
                                                 (float4*)ws0, (float4*)ws1, (float4*)acc);
        lgcn_scatter<<<(N_EDGES*16+BLK-1)/BLK, BLK, 0, stream>>>(adj_src, adj_dst, adj_vals,
                                                    (const float4*)ws0, ws1);
        lgcn_add_zero<<<grid_node, BLK, 0, stream>>>((float4*)acc, (const float4*)ws1, (float4*)ws0);
        lgcn_scatter<<<(N_EDGES*16+BLK-1)/BLK, BLK, 0, stream>>>(adj_src, adj_dst, adj_vals,
                                                    (const float4*)ws1, ws0);
        lgcn_add_zero<<<grid_node, BLK, 0, stream>>>((float4*)acc, (const float4*)ws0, (float4*)ws1);
        lgcn_scatter<<<(N_EDGES*16+BLK-1)/BLK, BLK, 0, stream>>>(adj_src, adj_dst, adj_vals,
                                                    (const float4*)ws0, ws1);
        lgcn_final<<<grid_node, BLK, 0, stream>>>((float4*)acc, (const float4*)ws1);
    }
}

// Round 4
// 626.121 us; speedup vs baseline: 1.3415x; 1.3415x over previous
//
#include <hip/hip_runtime.h>

// LightGCN propagation on MI355X — R12: R10 base + precomputed per-block
// bucket bases (k_part single-pass).
//
// R11 post-mortem: k_rhist (6M scattered global atomicAdd into 600KB) cost
// 237us with 187MB WRITE — device-scope atomics pay a memory-side RMW per op
// and don't coalesce across XCDs. NEVER histogram via global atomics here.
// Reverted to R10 (628us measured).
//
// R12: k_bhist stores its per-block LDS bucket counts to cnt_pb[block][bucket]
// (1.2MB, aliases dead pairs2 head). k_pscan scans each bucket column ->
// exact base per (block,bucket). k_part drops its whole first counting pass
// (24MB re-read + 6M LDS atomics) and the gcur global atomics.
//
// Inputs: [2] adj_src (6M int), [3] adj_dst (6M int), [4] adj_vals (6M f32),
//         [5] user_emb (100000x64 f32), [6] item_emb (50000x64 f32).
// Output: [150000x64] f32 = (e0+e1+e2+e3)/4.

#define NUM_USERS 100000
#define NUM_ITEMS 50000
#define N_NODES   150000
#define EMB       64
#define N_EDGES   6000000

#define ROWS_PER_B 256
#define NBUCKETS   586                        // ceil(150000/256)
#define NROWS_PAD  (NBUCKETS * ROWS_PER_B)    // 150016
#define PART_BLOCKS 512
#define CHUNK ((N_EDGES + PART_BLOCKS - 1) / PART_BLOCKS)   // 11719

constexpr int NODE_F4 = N_NODES * EMB / 4;   // 2,400,000
constexpr int USER_F4 = NUM_USERS * EMB / 4; // 1,600,000

typedef float f4v __attribute__((ext_vector_type(4)));   // 16B clang vector

__device__ __forceinline__ float bf2f(unsigned short u) {
    union { unsigned int i; float f; } x; x.i = ((unsigned int)u) << 16; return x.f;
}
__device__ __forceinline__ unsigned short f2bf(float f) {
    union { float f; unsigned int i; } x; x.f = f;
    unsigned int b = x.i;
    return (unsigned short)((b + 0x7FFFu + ((b >> 16) & 1u)) >> 16);  // RNE
}

// ---------------- phase 0: bucket histogram + scans ----------------

__global__ void k_zero(int* __restrict__ p, int n) {
    int i = blockIdx.x * blockDim.x + threadIdx.x;
    if (i < n) p[i] = 0;
}

// LDS bucket histogram; per-block counts stored to cnt_pb (coalesced) and
// aggregated into gcnt (586 global atomics per block only).
__global__ __launch_bounds__(256) void k_bhist(const int* __restrict__ dst,
                                               int* __restrict__ gcnt,
                                               int* __restrict__ cnt_pb) {
    __shared__ int cnt[NBUCKETS];
    int t = threadIdx.x;
    for (int i = t; i < NBUCKETS; i += 256) cnt[i] = 0;
    __syncthreads();
    int e0 = blockIdx.x * CHUNK;
    int e1 = min(e0 + CHUNK, N_EDGES);
    int e = e0 + t;
    for (; e + 7 * 256 < e1; e += 8 * 256) {
        int b_[8];
#pragma unroll
        for (int j = 0; j < 8; ++j)
            b_[j] = __builtin_nontemporal_load(dst + e + j * 256) >> 8;
#pragma unroll
        for (int j = 0; j < 8; ++j) atomicAdd(&cnt[b_[j]], 1);   // native ds_add
    }
    for (; e < e1; e += 256)
        atomicAdd(&cnt[__builtin_nontemporal_load(dst + e) >> 8], 1);
    __syncthreads();
    for (int i = t; i < NBUCKETS; i += 256) {
        int c = cnt[i];
        cnt_pb[blockIdx.x * NBUCKETS + i] = c;
        if (c) atomicAdd(&gcnt[i], c);
    }
}

__global__ void k_bscan(const int* __restrict__ gcnt, int* __restrict__ boff) {
    __shared__ int s[1024];
    int t = threadIdx.x;
    int x = (t < NBUCKETS) ? gcnt[t] : 0;
    s[t] = x;
    __syncthreads();
    for (int off = 1; off < 1024; off <<= 1) {
        int v = (t >= off) ? s[t - off] : 0;
        __syncthreads();
        s[t] += v;
        __syncthreads();
    }
    if (t < NBUCKETS) boff[t] = s[t] - x;
    if (t == 0) boff[NBUCKETS] = N_EDGES;
}

// column scan: cnt_pb[b][k] -> boff[k] + sum_{b'<b} cnt_pb[b'][k]  (in place)
__global__ __launch_bounds__(512) void k_pscan(const int* __restrict__ boff,
                                               int* __restrict__ cnt_pb) {
    __shared__ int s[PART_BLOCKS];
    int k = blockIdx.x;      // bucket
    int t = threadIdx.x;     // partition block
    int x = cnt_pb[t * NBUCKETS + k];
    s[t] = x;
    __syncthreads();
    for (int off = 1; off < PART_BLOCKS; off <<= 1) {
        int v = (t >= off) ? s[t - off] : 0;
        __syncthreads();
        s[t] += v;
        __syncthreads();
    }
    cnt_pb[t * NBUCKETS + k] = boff[k] + s[t] - x;   // exclusive base
}

// ---------------- phase 1: bucket partition (single pass) ----------------
// entry: x = src | (dstLocal<<18), y = val bits

__global__ __launch_bounds__(256) void k_part(const int* __restrict__ src,
                                              const int* __restrict__ dst,
                                              const float* __restrict__ val,
                                              const int* __restrict__ cnt_pb,
                                              int2* __restrict__ pairs) {
    __shared__ int cnt[NBUCKETS];      // intra-run cursors
    __shared__ int base[NBUCKETS];
    int t = threadIdx.x;
    for (int i = t; i < NBUCKETS; i += 256) {
        base[i] = cnt_pb[blockIdx.x * NBUCKETS + i];   // coalesced
        cnt[i] = 0;
    }
    __syncthreads();
    int e0 = blockIdx.x * CHUNK;
    int e1 = min(e0 + CHUNK, N_EDGES);
    int e = e0 + t;
    for (; e + 7 * 256 < e1; e += 8 * 256) {
        int d_[8], s_[8];
        float v_[8];
#pragma unroll
        for (int j = 0; j < 8; ++j)
            d_[j] = __builtin_nontemporal_load(dst + e + j * 256);
#pragma unroll
        for (int j = 0; j < 8; ++j)
            s_[j] = __builtin_nontemporal_load(src + e + j * 256);
#pragma unroll
        for (int j = 0; j < 8; ++j)
            v_[j] = __builtin_nontemporal_load(val + e + j * 256);
#pragma unroll
        for (int j = 0; j < 8; ++j) {
            int b_ = d_[j] >> 8;
            int o = atomicAdd(&cnt[b_], 1);
            pairs[base[b_] + o] = make_int2(s_[j] | ((d_[j] & 255) << 18),
                                            __float_as_int(v_[j]));
        }
    }
    for (; e < e1; e += 256) {
        int d0 = __builtin_nontemporal_load(dst + e);
        int s0 = __builtin_nontemporal_load(src + e);
        float v0 = __builtin_nontemporal_load(val + e);
        int b_ = d0 >> 8;
        int o0 = atomicAdd(&cnt[b_], 1);
        pairs[base[b_] + o0] = make_int2(s0 | ((d0 & 255) << 18),
                                         __float_as_int(v0));
    }
}

// ---------------- phase 2: per-bucket row histogram + scan + placement ----------------

__global__ __launch_bounds__(512) void k_sort(const int* __restrict__ boff,
                                              const int2* __restrict__ pairs1,
                                              int2* __restrict__ pairs2,
                                              int* __restrict__ row_ptr) {
    __shared__ int cnt[ROWS_PER_B];    // counts, then cursors
    __shared__ int s[ROWS_PER_B];
    int b = blockIdx.x;
    int t = threadIdx.x;
    if (t < ROWS_PER_B) cnt[t] = 0;
    __syncthreads();
    int beg = boff[b], end = boff[b + 1];
    {
        int e = beg + t;
        for (; e + 7 * 512 < end; e += 8 * 512) {
            int r_[8];
#pragma unroll
            for (int j = 0; j < 8; ++j)
                r_[j] = ((unsigned)pairs1[e + j * 512].x) >> 18;  // cached: reused by pass 2
#pragma unroll
            for (int j = 0; j < 8; ++j) atomicAdd(&cnt[r_[j]], 1);
        }
        for (; e < end; e += 512)
            atomicAdd(&cnt[((unsigned)pairs1[e].x) >> 18], 1);
    }
    __syncthreads();
    int x = (t < ROWS_PER_B) ? cnt[t] : 0;
    if (t < ROWS_PER_B) s[t] = x;
    __syncthreads();
    for (int off = 1; off < ROWS_PER_B; off <<= 1) {
        int v = (t >= off && t < ROWS_PER_B) ? s[t - off] : 0;
        __syncthreads();
        if (t < ROWS_PER_B) s[t] += v;
        __syncthreads();
    }
    if (t < ROWS_PER_B) {
        int ex = beg + s[t] - x;
        row_ptr[b * ROWS_PER_B + t] = ex;
        cnt[t] = ex;
    }
    if (b == NBUCKETS - 1 && t == ROWS_PER_B - 1) row_ptr[NROWS_PAD] = N_EDGES;
    __syncthreads();
    const long* p1l = (const long*)pairs1;
    {
        int e = beg + t;
        for (; e + 7 * 512 < end; e += 8 * 512) {
            long q[8];
#pragma unroll
            for (int j = 0; j < 8; ++j)
                q[j] = __builtin_nontemporal_load(p1l + e + j * 512);  // last read: NT
#pragma unroll
            for (int j = 0; j < 8; ++j) {
                int x0 = (int)q[j], y0 = (int)(q[j] >> 32);
                int pos = atomicAdd(&cnt[((unsigned)x0) >> 18], 1);
                pairs2[pos] = make_int2(x0 & 0x3FFFF, y0);
            }
        }
        for (; e < end; e += 512) {
            long q0 = __builtin_nontemporal_load(p1l + e);
            int x0 = (int)q0, y0 = (int)(q0 >> 32);
            int pos = atomicAdd(&cnt[((unsigned)x0) >> 18], 1);
            pairs2[pos] = make_int2(x0 & 0x3FFFF, y0);
        }
    }
}

// ---------------- phase 3: propagation ----------------

__global__ void k_init(const f4v* __restrict__ ue, const f4v* __restrict__ ie,
                       ushort4* __restrict__ e0b, f4v* __restrict__ acc) {
    int i = blockIdx.x * blockDim.x + threadIdx.x;
    if (i >= NODE_F4) return;
    f4v v = (i < USER_F4) ? __builtin_nontemporal_load(ue + i)
                          : __builtin_nontemporal_load(ie + i - USER_F4);
    __builtin_nontemporal_store(v, acc + i);     // re-read only in the final layer
    e0b[i] = make_ushort4(f2bf(v.x), f2bf(v.y), f2bf(v.z), f2bf(v.w));
}

// 16 lanes/row; lane owns 4 channels (8B ushort4 gather). Unroll-8: 8 pair
// loads issued, then 8 independent gathers in flight. Layers 0/1: nxt only.
__global__ __launch_bounds__(256) void k_spmm(const int* __restrict__ row_ptr,
                                              const long* __restrict__ pairs,
                                              const ushort4* __restrict__ cur,
                                              ushort4* __restrict__ nxt) {
    int tid = blockIdx.x * blockDim.x + threadIdx.x;
    int row = tid >> 4;
    if (row >= N_NODES) return;
    int c = tid & 15;
    int beg = row_ptr[row];
    int end = row_ptr[row + 1];
    float4 r = make_float4(0.f, 0.f, 0.f, 0.f);
    int k = beg;
    for (; k + 7 < end; k += 8) {
        long p[8];
        ushort4 g[8];
#pragma unroll
        for (int j = 0; j < 8; ++j) p[j] = pairs[k + j];
#pragma unroll
        for (int j = 0; j < 8; ++j) g[j] = cur[(long)(int)(p[j] & 0x3FFFF) * 16 + c];
#pragma unroll
        for (int j = 0; j < 8; ++j) {
            float v = __int_as_float((int)(p[j] >> 32));
            r.x += v * bf2f(g[j].x);
            r.y += v * bf2f(g[j].y);
            r.z += v * bf2f(g[j].z);
            r.w += v * bf2f(g[j].w);
        }
    }
    for (; k < end; ++k) {
        long p0 = pairs[k];
        ushort4 g0 = cur[(long)(int)(p0 & 0x3FFFF) * 16 + c];
        float v0 = __int_as_float((int)(p0 >> 32));
        r.x += v0 * bf2f(g0.x);
        r.y += v0 * bf2f(g0.y);
        r.z += v0 * bf2f(g0.z);
        r.w += v0 * bf2f(g0.w);
    }
    nxt[(long)row * 16 + c] = make_ushort4(f2bf(r.x), f2bf(r.y), f2bf(r.z), f2bf(r.w));
}

// Final layer: r = SpMM(e2); acc = (acc + e1 + e2 + r) * 0.25
__global__ __launch_bounds__(256) void k_spmm_fin(const int* __restrict__ row_ptr,
                                                  const long* __restrict__ pairs,
                                                  const ushort4* __restrict__ cur,  // e2b
                                                  const ushort4* __restrict__ e1b,
                                                  float4* __restrict__ acc) {
    int tid = blockIdx.x * blockDim.x + threadIdx.x;
    int row = tid >> 4;
    if (row >= N_NODES) return;
    int c = tid & 15;
    int beg = row_ptr[row];
    int end = row_ptr[row + 1];
    float4 r = make_float4(0.f, 0.f, 0.f, 0.f);
    int k = beg;
    for (; k + 7 < end; k += 8) {
        long p[8];
        ushort4 g[8];
#pragma unroll
        for (int j = 0; j < 8; ++j) p[j] = pairs[k + j];
#pragma unroll
        for (int j = 0; j < 8; ++j) g[j] = cur[(long)(int)(p[j] & 0x3FFFF) * 16 + c];
#pragma unroll
        for (int j = 0; j < 8; ++j) {
            float v = __int_as_float((int)(p[j] >> 32));
            r.x += v * bf2f(g[j].x);
            r.y += v * bf2f(g[j].y);
            r.z += v * bf2f(g[j].z);
            r.w += v * bf2f(g[j].w);
        }
    }
    for (; k < end; ++k) {
        long p0 = pairs[k];
        ushort4 g0 = cur[(long)(int)(p0 & 0x3FFFF) * 16 + c];
        float v0 = __int_as_float((int)(p0 >> 32));
        r.x += v0 * bf2f(g0.x);
        r.y += v0 * bf2f(g0.y);
        r.z += v0 * bf2f(g0.z);
        r.w += v0 * bf2f(g0.w);
    }
    long o = (long)row * 16 + c;
    ushort4 e1 = e1b[o];
    ushort4 e2 = cur[o];
    float4 a = acc[o];
    a.x = (a.x + bf2f(e1.x) + bf2f(e2.x) + r.x) * 0.25f;
    a.y = (a.y + bf2f(e1.y) + bf2f(e2.y) + r.y) * 0.25f;
    a.z = (a.z + bf2f(e1.z) + bf2f(e2.z) + r.z) * 0.25f;
    a.w = (a.w + bf2f(e1.w) + bf2f(e2.w) + r.w) * 0.25f;
    acc[o] = a;
}

// ---------------- R0 fallback (atomic scatter) for small ws ----------------

__global__ void lgcn_init(const float4* __restrict__ user_emb,
                          const float4* __restrict__ item_emb,
                          float4* __restrict__ cur, float4* __restrict__ nxt,
                          float4* __restrict__ acc) {
    int i = blockIdx.x * blockDim.x + threadIdx.x;
    if (i >= NODE_F4) return;
    float4 v = (i < USER_F4) ? user_emb[i] : item_emb[i - USER_F4];
    cur[i] = v; acc[i] = v; nxt[i] = make_float4(0.f, 0.f, 0.f, 0.f);
}

__global__ void lgcn_scatter(const int* __restrict__ src, const int* __restrict__ dst,
                             const float* __restrict__ val,
                             const float4* __restrict__ cur, float* __restrict__ nxt) {
    int tid = blockIdx.x * blockDim.x + threadIdx.x;
    int e = tid >> 4;
    if (e >= N_EDGES) return;
    int c = tid & 15;
    int s = src[e]; int d = dst[e]; float v = val[e];
    float4 m = cur[(long)s * 16 + c];
    float* p = nxt + (long)d * 64 + c * 4;
    unsafeAtomicAdd(p + 0, v * m.x);
    unsafeAtomicAdd(p + 1, v * m.y);
    unsafeAtomicAdd(p + 2, v * m.z);
    unsafeAtomicAdd(p + 3, v * m.w);
}

__global__ void lgcn_add_zero(float4* __restrict__ acc, const float4* __restrict__ nxt,
                              float4* __restrict__ other) {
    int i = blockIdx.x * blockDim.x + threadIdx.x;
    if (i >= NODE_F4) return;
    float4 a = acc[i]; float4 n = nxt[i];
    a.x += n.x; a.y += n.y; a.z += n.z; a.w += n.w;
    acc[i] = a;
    other[i] = make_float4(0.f, 0.f, 0.f, 0.f);
}

__global__ void lgcn_final(float4* __restrict__ acc, const float4* __restrict__ nxt) {
    int i = blockIdx.x * blockDim.x + threadIdx.x;
    if (i >= NODE_F4) return;
    float4 a = acc[i]; float4 n = nxt[i];
    a.x = (a.x + n.x) * 0.25f; a.y = (a.y + n.y) * 0.25f;
    a.z = (a.z + n.z) * 0.25f; a.w = (a.w + n.w) * 0.25f;
    acc[i] = a;
}

// ---------------- launch ----------------

extern "C" void kernel_launch(void* const* d_in, const int* in_sizes, int n_in,
                              void* d_out, int out_size, void* d_ws, size_t ws_size,
                              hipStream_t stream) {
    const int*    adj_src  = (const int*)d_in[2];
    const int*    adj_dst  = (const int*)d_in[3];
    const float*  adj_vals = (const float*)d_in[4];
    float* acc = (float*)d_out;

    const int BLK = 256;
    const int grid_node  = (NODE_F4 + BLK - 1) / BLK;        // 9375
    const int grid_row16 = (N_NODES * 16 + BLK - 1) / BLK;   // 9375

    // workspace layout (bytes):
    //   [0, 48MB)      pairs2; head [0, 1.2MB) transiently cnt_pb (dead
    //                  after k_part, before pairs2 is written)
    //   [48, 96MB)     pairs1; after k_sort reused: e0b (19.2) + e1b (19.2)
    //   [96, 115.2MB)  e2b
    //   [115.2MB, ...) row_ptr (150017 ints), gcnt, boff
    const size_t SZ_PAIRS = (size_t)N_EDGES * 8;             // 48,000,000
    const size_t SZ_BF    = (size_t)N_NODES * EMB * 2;       // 19,200,000
    const size_t SZ_RP    = 600320;                          // 150017 ints, padded
    const size_t SZ_B     = 4096;
    const size_t NEEDED   = 2 * SZ_PAIRS + SZ_BF + SZ_RP + 3 * SZ_B;  // ~115.8 MB

    if (ws_size >= NEEDED) {
        char* w = (char*)d_ws;
        int2*    pairs2 = (int2*)(w);
        int*     cnt_pb = (int*)(w);                          // aliases pairs2 head
        int2*    pairs1 = (int2*)(w + SZ_PAIRS);
        ushort4* e0b    = (ushort4*)(w + SZ_PAIRS);           // aliases pairs1
        ushort4* e1b    = (ushort4*)(w + SZ_PAIRS + SZ_BF);   // aliases pairs1
        ushort4* e2b    = (ushort4*)(w + 2 * SZ_PAIRS);
        int*  row_ptr= (int*)(w + 2 * SZ_PAIRS + SZ_BF);
        int*  gcnt   = (int*)(w + 2 * SZ_PAIRS + SZ_BF + SZ_RP);
        int*  boff   = (int*)(w + 2 * SZ_PAIRS + SZ_BF + SZ_RP + SZ_B);

        // phase 0: bucket counts (global + per-block) -> offsets + bases
        k_zero<<<(NBUCKETS + BLK - 1) / BLK, BLK, 0, stream>>>(gcnt, NBUCKETS);
        k_bhist<<<PART_BLOCKS, BLK, 0, stream>>>(adj_dst, gcnt, cnt_pb);
        k_bscan<<<1, 1024, 0, stream>>>(gcnt, boff);
        k_pscan<<<NBUCKETS, PART_BLOCKS, 0, stream>>>(boff, cnt_pb);

        // phase 1: bucket partition (single pass, no counting, no global atomics)
        k_part<<<PART_BLOCKS, BLK, 0, stream>>>(adj_src, adj_dst, adj_vals,
                                                cnt_pb, pairs1);

        // phase 2: per-bucket row sort -> pairs2 + row_ptr (cnt_pb dead now)
        k_sort<<<NBUCKETS, 512, 0, stream>>>(boff, pairs1, pairs2, row_ptr);

        // phase 3: propagation (pairs1 region reused for e0b/e1b)
        k_init<<<grid_node, BLK, 0, stream>>>((const f4v*)d_in[5], (const f4v*)d_in[6],
                                              e0b, (f4v*)acc);
        k_spmm<<<grid_row16, BLK, 0, stream>>>(row_ptr, (const long*)pairs2, e0b, e1b);
        k_spmm<<<grid_row16, BLK, 0, stream>>>(row_ptr, (const long*)pairs2, e1b, e2b);
        k_spmm_fin<<<grid_row16, BLK, 0, stream>>>(row_ptr, (const long*)pairs2, e2b,
                                                   e1b, (float4*)acc);
    } else {
        // R0 fallback: atomic scatter
        const float4* user_emb = (const float4*)d_in[5];
        const float4* item_emb = (const float4*)d_in[6];
        float* ws0 = (float*)d_ws;
        float* ws1 = ws0 + (size_t)N_NODES * EMB;
        lgcn_init<<<grid_node, BLK, 0, stream>>>(user_emb, item_emb,
                                                 (float4*)ws0, (float4*)ws1, (float4*)acc);
        lgcn_scatter<<<(N_EDGES*16+BLK-1)/BLK, BLK, 0, stream>>>(adj_src, adj_dst, adj_vals,
                                                    (const float4*)ws0, ws1);
        lgcn_add_zero<<<grid_node, BLK, 0, stream>>>((float4*)acc, (const float4*)ws1, (float4*)ws0);
        lgcn_scatter<<<(N_EDGES*16+BLK-1)/BLK, BLK, 0, stream>>>(adj_src, adj_dst, adj_vals,
                                                    (const float4*)ws1, ws0);
        lgcn_add_zero<<<grid_node, BLK, 0, stream>>>((float4*)acc, (const float4*)ws0, (float4*)ws1);
        lgcn_scatter<<<(N_EDGES*16+BLK-1)/BLK, BLK, 0, stream>>>(adj_src, adj_dst, adj_vals,
                                                    (const float4*)ws0, ws1);
        lgcn_final<<<grid_node, BLK, 0, stream>>>((float4*)acc, (const float4*)ws1);
    }
}

// Round 5
// 607.350 us; speedup vs baseline: 1.3830x; 1.0309x over previous
//
#include <hip/hip_runtime.h>

// LightGCN propagation on MI355X — R13: over-allocated buckets delete the
// whole pre-count pipeline; k_sort at 1024 threads.
//
// R12 post-mortem: removing k_part's count pass was net-zero (626 vs 628) —
// the streaming LDS-histogram pass is only ~12-15us at 8 waves/CU; k_pscan
// ate the savings. Lesson: prep cost is in scattered-write phases + kernel
// count, not streaming counts.
//
// R13: pairs1 buckets padded to CAP=10952 (mean 10240 + 7sigma; overflow
// P~1e-9 on the fixed input, and overflow lands in the later-written e2b
// region — not OOB). k_part = R10-proven self-count + claim, with gcur
// pre-set to k*CAP by k_ginit -> k_zero/k_bhist/k_bscan/k_pscan all deleted.
// Exact boff recovered from gcur fills by k_fill (1-block scan); k_sort reads
// padded ranges [k*CAP, gcur[k]) and writes dense pairs2 + row_ptr.
// k_sort: 512 -> 1024 threads (TLP knob on the latency-bound chain).
//
// Inputs: [2] adj_src (6M int), [3] adj_dst (6M int), [4] adj_vals (6M f32),
//         [5] user_emb (100000x64 f32), [6] item_emb (50000x64 f32).
// Output: [150000x64] f32 = (e0+e1+e2+e3)/4.

#define NUM_USERS 100000
#define NUM_ITEMS 50000
#define N_NODES   150000
#define EMB       64
#define N_EDGES   6000000

#define ROWS_PER_B 256
#define NBUCKETS   586                        // ceil(150000/256)
#define NROWS_PAD  (NBUCKETS * ROWS_PER_B)    // 150016
#define PART_BLOCKS 512
#define CHUNK ((N_EDGES + PART_BLOCKS - 1) / PART_BLOCKS)   // 11719
#define CAP_B 10952                           // 10240 + 7 sigma, padded bucket cap

constexpr int NODE_F4 = N_NODES * EMB / 4;   // 2,400,000
constexpr int USER_F4 = NUM_USERS * EMB / 4; // 1,600,000

typedef float f4v __attribute__((ext_vector_type(4)));   // 16B clang vector

__device__ __forceinline__ float bf2f(unsigned short u) {
    union { unsigned int i; float f; } x; x.i = ((unsigned int)u) << 16; return x.f;
}
__device__ __forceinline__ unsigned short f2bf(float f) {
    union { float f; unsigned int i; } x; x.f = f;
    unsigned int b = x.i;
    return (unsigned short)((b + 0x7FFFu + ((b >> 16) & 1u)) >> 16);  // RNE
}

// ================= tier-1 (padded-bucket) kernels =================

__global__ void k_ginit(int* __restrict__ gcur) {
    int i = blockIdx.x * blockDim.x + threadIdx.x;
    if (i < NBUCKETS) gcur[i] = i * CAP_B;
}

// self-count + claim + scatter (R10-proven structure; bases claimed from
// gcur pre-set to k*CAP — no pre-counting kernels needed)
__global__ __launch_bounds__(256) void k_part(const int* __restrict__ src,
                                              const int* __restrict__ dst,
                                              const float* __restrict__ val,
                                              int* __restrict__ gcur,
                                              int2* __restrict__ pairs) {
    __shared__ int cnt[NBUCKETS];
    __shared__ int base[NBUCKETS];
    int t = threadIdx.x;
    for (int i = t; i < NBUCKETS; i += 256) cnt[i] = 0;
    __syncthreads();
    int e0 = blockIdx.x * CHUNK;
    int e1 = min(e0 + CHUNK, N_EDGES);
    {
        int e = e0 + t;
        for (; e + 7 * 256 < e1; e += 8 * 256) {
            int b_[8];
#pragma unroll
            for (int j = 0; j < 8; ++j)
                b_[j] = __builtin_nontemporal_load(dst + e + j * 256) >> 8;
#pragma unroll
            for (int j = 0; j < 8; ++j) atomicAdd(&cnt[b_[j]], 1);
        }
        for (; e < e1; e += 256)
            atomicAdd(&cnt[__builtin_nontemporal_load(dst + e) >> 8], 1);
    }
    __syncthreads();
    for (int i = t; i < NBUCKETS; i += 256) {
        int c = cnt[i];
        base[i] = c ? atomicAdd(&gcur[i], c) : 0;
        cnt[i] = 0;
    }
    __syncthreads();
    {
        int e = e0 + t;
        for (; e + 7 * 256 < e1; e += 8 * 256) {
            int d_[8], s_[8];
            float v_[8];
#pragma unroll
            for (int j = 0; j < 8; ++j)
                d_[j] = __builtin_nontemporal_load(dst + e + j * 256);
#pragma unroll
            for (int j = 0; j < 8; ++j)
                s_[j] = __builtin_nontemporal_load(src + e + j * 256);
#pragma unroll
            for (int j = 0; j < 8; ++j)
                v_[j] = __builtin_nontemporal_load(val + e + j * 256);
#pragma unroll
            for (int j = 0; j < 8; ++j) {
                int b_ = d_[j] >> 8;
                int o = atomicAdd(&cnt[b_], 1);
                pairs[base[b_] + o] = make_int2(s_[j] | ((d_[j] & 255) << 18),
                                                __float_as_int(v_[j]));
            }
        }
        for (; e < e1; e += 256) {
            int d0 = __builtin_nontemporal_load(dst + e);
            int s0 = __builtin_nontemporal_load(src + e);
            float v0 = __builtin_nontemporal_load(val + e);
            int b_ = d0 >> 8;
            int o0 = atomicAdd(&cnt[b_], 1);
            pairs[base[b_] + o0] = make_int2(s0 | ((d0 & 255) << 18),
                                             __float_as_int(v0));
        }
    }
}

// fills = gcur[k] - k*CAP -> exclusive scan -> exact dense bucket offsets
__global__ void k_fill(const int* __restrict__ gcur, int* __restrict__ boff) {
    __shared__ int s[1024];
    int t = threadIdx.x;
    int x = (t < NBUCKETS) ? (gcur[t] - t * CAP_B) : 0;
    s[t] = x;
    __syncthreads();
    for (int off = 1; off < 1024; off <<= 1) {
        int v = (t >= off) ? s[t - off] : 0;
        __syncthreads();
        s[t] += v;
        __syncthreads();
    }
    if (t < NBUCKETS) boff[t] = s[t] - x;
    if (t == 0) boff[NBUCKETS] = N_EDGES;
}

// per-bucket row sort from padded source range; 1024 threads.
__global__ __launch_bounds__(1024) void k_sortA(const int* __restrict__ gcur,
                                                const int* __restrict__ boff,
                                                const int2* __restrict__ pairs1,
                                                int2* __restrict__ pairs2,
                                                int* __restrict__ row_ptr) {
    __shared__ int cnt[ROWS_PER_B];    // counts, then cursors
    __shared__ int s[ROWS_PER_B];
    int b = blockIdx.x;
    int t = threadIdx.x;
    if (t < ROWS_PER_B) cnt[t] = 0;
    __syncthreads();
    int beg = b * CAP_B;
    int end = gcur[b];
    {
        int e = beg + t;
        for (; e + 7 * 1024 < end; e += 8 * 1024) {
            int r_[8];
#pragma unroll
            for (int j = 0; j < 8; ++j)
                r_[j] = ((unsigned)pairs1[e + j * 1024].x) >> 18;  // cached: reused by pass 2
#pragma unroll
            for (int j = 0; j < 8; ++j) atomicAdd(&cnt[r_[j]], 1);
        }
        for (; e < end; e += 1024)
            atomicAdd(&cnt[((unsigned)pairs1[e].x) >> 18], 1);
    }
    __syncthreads();
    int x = (t < ROWS_PER_B) ? cnt[t] : 0;
    if (t < ROWS_PER_B) s[t] = x;
    __syncthreads();
    for (int off = 1; off < ROWS_PER_B; off <<= 1) {
        int v = (t >= off && t < ROWS_PER_B) ? s[t - off] : 0;
        __syncthreads();
        if (t < ROWS_PER_B) s[t] += v;
        __syncthreads();
    }
    if (t < ROWS_PER_B) {
        int ex = boff[b] + s[t] - x;
        row_ptr[b * ROWS_PER_B + t] = ex;
        cnt[t] = ex;
    }
    if (b == NBUCKETS - 1 && t == 0) row_ptr[NROWS_PAD] = N_EDGES;
    __syncthreads();
    const long* p1l = (const long*)pairs1;
    {
        int e = beg + t;
        for (; e + 7 * 1024 < end; e += 8 * 1024) {
            long q[8];
#pragma unroll
            for (int j = 0; j < 8; ++j)
                q[j] = __builtin_nontemporal_load(p1l + e + j * 1024);  // last read: NT
#pragma unroll
            for (int j = 0; j < 8; ++j) {
                int x0 = (int)q[j], y0 = (int)(q[j] >> 32);
                int pos = atomicAdd(&cnt[((unsigned)x0) >> 18], 1);
                pairs2[pos] = make_int2(x0 & 0x3FFFF, y0);
            }
        }
        for (; e < end; e += 1024) {
            long q0 = __builtin_nontemporal_load(p1l + e);
            int x0 = (int)q0, y0 = (int)(q0 >> 32);
            int pos = atomicAdd(&cnt[((unsigned)x0) >> 18], 1);
            pairs2[pos] = make_int2(x0 & 0x3FFFF, y0);
        }
    }
}

// ================= tier-2 (R12 exact) kernels =================

__global__ void k_zero(int* __restrict__ p, int n) {
    int i = blockIdx.x * blockDim.x + threadIdx.x;
    if (i < n) p[i] = 0;
}

__global__ __launch_bounds__(256) void k_bhist(const int* __restrict__ dst,
                                               int* __restrict__ gcnt,
                                               int* __restrict__ cnt_pb) {
    __shared__ int cnt[NBUCKETS];
    int t = threadIdx.x;
    for (int i = t; i < NBUCKETS; i += 256) cnt[i] = 0;
    __syncthreads();
    int e0 = blockIdx.x * CHUNK;
    int e1 = min(e0 + CHUNK, N_EDGES);
    int e = e0 + t;
    for (; e + 7 * 256 < e1; e += 8 * 256) {
        int b_[8];
#pragma unroll
        for (int j = 0; j < 8; ++j)
            b_[j] = __builtin_nontemporal_load(dst + e + j * 256) >> 8;
#pragma unroll
        for (int j = 0; j < 8; ++j) atomicAdd(&cnt[b_[j]], 1);
    }
    for (; e < e1; e += 256)
        atomicAdd(&cnt[__builtin_nontemporal_load(dst + e) >> 8], 1);
    __syncthreads();
    for (int i = t; i < NBUCKETS; i += 256) {
        int c = cnt[i];
        cnt_pb[blockIdx.x * NBUCKETS + i] = c;
        if (c) atomicAdd(&gcnt[i], c);
    }
}

__global__ void k_bscan(const int* __restrict__ gcnt, int* __restrict__ boff) {
    __shared__ int s[1024];
    int t = threadIdx.x;
    int x = (t < NBUCKETS) ? gcnt[t] : 0;
    s[t] = x;
    __syncthreads();
    for (int off = 1; off < 1024; off <<= 1) {
        int v = (t >= off) ? s[t - off] : 0;
        __syncthreads();
        s[t] += v;
        __syncthreads();
    }
    if (t < NBUCKETS) boff[t] = s[t] - x;
    if (t == 0) boff[NBUCKETS] = N_EDGES;
}

__global__ __launch_bounds__(512) void k_pscan(const int* __restrict__ boff,
                                               int* __restrict__ cnt_pb) {
    __shared__ int s[PART_BLOCKS];
    int k = blockIdx.x;
    int t = threadIdx.x;
    int x = cnt_pb[t * NBUCKETS + k];
    s[t] = x;
    __syncthreads();
    for (int off = 1; off < PART_BLOCKS; off <<= 1) {
        int v = (t >= off) ? s[t - off] : 0;
        __syncthreads();
        s[t] += v;
        __syncthreads();
    }
    cnt_pb[t * NBUCKETS + k] = boff[k] + s[t] - x;
}

__global__ __launch_bounds__(256) void k_part2(const int* __restrict__ src,
                                               const int* __restrict__ dst,
                                               const float* __restrict__ val,
                                               const int* __restrict__ cnt_pb,
                                               int2* __restrict__ pairs) {
    __shared__ int cnt[NBUCKETS];
    __shared__ int base[NBUCKETS];
    int t = threadIdx.x;
    for (int i = t; i < NBUCKETS; i += 256) {
        base[i] = cnt_pb[blockIdx.x * NBUCKETS + i];
        cnt[i] = 0;
    }
    __syncthreads();
    int e0 = blockIdx.x * CHUNK;
    int e1 = min(e0 + CHUNK, N_EDGES);
    int e = e0 + t;
    for (; e + 7 * 256 < e1; e += 8 * 256) {
        int d_[8], s_[8];
        float v_[8];
#pragma unroll
        for (int j = 0; j < 8; ++j)
            d_[j] = __builtin_nontemporal_load(dst + e + j * 256);
#pragma unroll
        for (int j = 0; j < 8; ++j)
            s_[j] = __builtin_nontemporal_load(src + e + j * 256);
#pragma unroll
        for (int j = 0; j < 8; ++j)
            v_[j] = __builtin_nontemporal_load(val + e + j * 256);
#pragma unroll
        for (int j = 0; j < 8; ++j) {
            int b_ = d_[j] >> 8;
            int o = atomicAdd(&cnt[b_], 1);
            pairs[base[b_] + o] = make_int2(s_[j] | ((d_[j] & 255) << 18),
                                            __float_as_int(v_[j]));
        }
    }
    for (; e < e1; e += 256) {
        int d0 = __builtin_nontemporal_load(dst + e);
        int s0 = __builtin_nontemporal_load(src + e);
        float v0 = __builtin_nontemporal_load(val + e);
        int b_ = d0 >> 8;
        int o0 = atomicAdd(&cnt[b_], 1);
        pairs[base[b_] + o0] = make_int2(s0 | ((d0 & 255) << 18),
                                         __float_as_int(v0));
    }
}

__global__ __launch_bounds__(512) void k_sort(const int* __restrict__ boff,
                                              const int2* __restrict__ pairs1,
                                              int2* __restrict__ pairs2,
                                              int* __restrict__ row_ptr) {
    __shared__ int cnt[ROWS_PER_B];
    __shared__ int s[ROWS_PER_B];
    int b = blockIdx.x;
    int t = threadIdx.x;
    if (t < ROWS_PER_B) cnt[t] = 0;
    __syncthreads();
    int beg = boff[b], end = boff[b + 1];
    {
        int e = beg + t;
        for (; e + 7 * 512 < end; e += 8 * 512) {
            int r_[8];
#pragma unroll
            for (int j = 0; j < 8; ++j)
                r_[j] = ((unsigned)pairs1[e + j * 512].x) >> 18;
#pragma unroll
            for (int j = 0; j < 8; ++j) atomicAdd(&cnt[r_[j]], 1);
        }
        for (; e < end; e += 512)
            atomicAdd(&cnt[((unsigned)pairs1[e].x) >> 18], 1);
    }
    __syncthreads();
    int x = (t < ROWS_PER_B) ? cnt[t] : 0;
    if (t < ROWS_PER_B) s[t] = x;
    __syncthreads();
    for (int off = 1; off < ROWS_PER_B; off <<= 1) {
        int v = (t >= off && t < ROWS_PER_B) ? s[t - off] : 0;
        __syncthreads();
        if (t < ROWS_PER_B) s[t] += v;
        __syncthreads();
    }
    if (t < ROWS_PER_B) {
        int ex = beg + s[t] - x;
        row_ptr[b * ROWS_PER_B + t] = ex;
        cnt[t] = ex;
    }
    if (b == NBUCKETS - 1 && t == 0) row_ptr[NROWS_PAD] = N_EDGES;
    __syncthreads();
    const long* p1l = (const long*)pairs1;
    {
        int e = beg + t;
        for (; e + 7 * 512 < end; e += 8 * 512) {
            long q[8];
#pragma unroll
            for (int j = 0; j < 8; ++j)
                q[j] = __builtin_nontemporal_load(p1l + e + j * 512);
#pragma unroll
            for (int j = 0; j < 8; ++j) {
                int x0 = (int)q[j], y0 = (int)(q[j] >> 32);
                int pos = atomicAdd(&cnt[((unsigned)x0) >> 18], 1);
                pairs2[pos] = make_int2(x0 & 0x3FFFF, y0);
            }
        }
        for (; e < end; e += 512) {
            long q0 = __builtin_nontemporal_load(p1l + e);
            int x0 = (int)q0, y0 = (int)(q0 >> 32);
            int pos = atomicAdd(&cnt[((unsigned)x0) >> 18], 1);
            pairs2[pos] = make_int2(x0 & 0x3FFFF, y0);
        }
    }
}

// ---------------- phase 3: propagation ----------------

__global__ void k_init(const f4v* __restrict__ ue, const f4v* __restrict__ ie,
                       ushort4* __restrict__ e0b, f4v* __restrict__ acc) {
    int i = blockIdx.x * blockDim.x + threadIdx.x;
    if (i >= NODE_F4) return;
    f4v v = (i < USER_F4) ? __builtin_nontemporal_load(ue + i)
                          : __builtin_nontemporal_load(ie + i - USER_F4);
    __builtin_nontemporal_store(v, acc + i);     // re-read only in the final layer
    e0b[i] = make_ushort4(f2bf(v.x), f2bf(v.y), f2bf(v.z), f2bf(v.w));
}

// 16 lanes/row; lane owns 4 channels (8B ushort4 gather). Unroll-8: 8 pair
// loads issued, then 8 independent gathers in flight. Layers 0/1: nxt only.
__global__ __launch_bounds__(256) void k_spmm(const int* __restrict__ row_ptr,
                                              const long* __restrict__ pairs,
                                              const ushort4* __restrict__ cur,
                                              ushort4* __restrict__ nxt) {
    int tid = blockIdx.x * blockDim.x + threadIdx.x;
    int row = tid >> 4;
    if (row >= N_NODES) return;
    int c = tid & 15;
    int beg = row_ptr[row];
    int end = row_ptr[row + 1];
    float4 r = make_float4(0.f, 0.f, 0.f, 0.f);
    int k = beg;
    for (; k + 7 < end; k += 8) {
        long p[8];
        ushort4 g[8];
#pragma unroll
        for (int j = 0; j < 8; ++j) p[j] = pairs[k + j];
#pragma unroll
        for (int j = 0; j < 8; ++j) g[j] = cur[(long)(int)(p[j] & 0x3FFFF) * 16 + c];
#pragma unroll
        for (int j = 0; j < 8; ++j) {
            float v = __int_as_float((int)(p[j] >> 32));
            r.x += v * bf2f(g[j].x);
            r.y += v * bf2f(g[j].y);
            r.z += v * bf2f(g[j].z);
            r.w += v * bf2f(g[j].w);
        }
    }
    for (; k < end; ++k) {
        long p0 = pairs[k];
        ushort4 g0 = cur[(long)(int)(p0 & 0x3FFFF) * 16 + c];
        float v0 = __int_as_float((int)(p0 >> 32));
        r.x += v0 * bf2f(g0.x);
        r.y += v0 * bf2f(g0.y);
        r.z += v0 * bf2f(g0.z);
        r.w += v0 * bf2f(g0.w);
    }
    nxt[(long)row * 16 + c] = make_ushort4(f2bf(r.x), f2bf(r.y), f2bf(r.z), f2bf(r.w));
}

// Final layer: r = SpMM(e2); acc = (acc + e1 + e2 + r) * 0.25
__global__ __launch_bounds__(256) void k_spmm_fin(const int* __restrict__ row_ptr,
                                                  const long* __restrict__ pairs,
                                                  const ushort4* __restrict__ cur,  // e2b
                                                  const ushort4* __restrict__ e1b,
                                                  float4* __restrict__ acc) {
    int tid = blockIdx.x * blockDim.x + threadIdx.x;
    int row = tid >> 4;
    if (row >= N_NODES) return;
    int c = tid & 15;
    int beg = row_ptr[row];
    int end = row_ptr[row + 1];
    float4 r = make_float4(0.f, 0.f, 0.f, 0.f);
    int k = beg;
    for (; k + 7 < end; k += 8) {
        long p[8];
        ushort4 g[8];
#pragma unroll
        for (int j = 0; j < 8; ++j) p[j] = pairs[k + j];
#pragma unroll
        for (int j = 0; j < 8; ++j) g[j] = cur[(long)(int)(p[j] & 0x3FFFF) * 16 + c];
#pragma unroll
        for (int j = 0; j < 8; ++j) {
            float v = __int_as_float((int)(p[j] >> 32));
            r.x += v * bf2f(g[j].x);
            r.y += v * bf2f(g[j].y);
            r.z += v * bf2f(g[j].z);
            r.w += v * bf2f(g[j].w);
        }
    }
    for (; k < end; ++k) {
        long p0 = pairs[k];
        ushort4 g0 = cur[(long)(int)(p0 & 0x3FFFF) * 16 + c];
        float v0 = __int_as_float((int)(p0 >> 32));
        r.x += v0 * bf2f(g0.x);
        r.y += v0 * bf2f(g0.y);
        r.z += v0 * bf2f(g0.z);
        r.w += v0 * bf2f(g0.w);
    }
    long o = (long)row * 16 + c;
    ushort4 e1 = e1b[o];
    ushort4 e2 = cur[o];
    float4 a = acc[o];
    a.x = (a.x + bf2f(e1.x) + bf2f(e2.x) + r.x) * 0.25f;
    a.y = (a.y + bf2f(e1.y) + bf2f(e2.y) + r.y) * 0.25f;
    a.z = (a.z + bf2f(e1.z) + bf2f(e2.z) + r.z) * 0.25f;
    a.w = (a.w + bf2f(e1.w) + bf2f(e2.w) + r.w) * 0.25f;
    acc[o] = a;
}

// ---------------- R0 fallback (atomic scatter) for small ws ----------------

__global__ void lgcn_init(const float4* __restrict__ user_emb,
                          const float4* __restrict__ item_emb,
                          float4* __restrict__ cur, float4* __restrict__ nxt,
                          float4* __restrict__ acc) {
    int i = blockIdx.x * blockDim.x + threadIdx.x;
    if (i >= NODE_F4) return;
    float4 v = (i < USER_F4) ? user_emb[i] : item_emb[i - USER_F4];
    cur[i] = v; acc[i] = v; nxt[i] = make_float4(0.f, 0.f, 0.f, 0.f);
}

__global__ void lgcn_scatter(const int* __restrict__ src, const int* __restrict__ dst,
                             const float* __restrict__ val,
                             const float4* __restrict__ cur, float* __restrict__ nxt) {
    int tid = blockIdx.x * blockDim.x + threadIdx.x;
    int e = tid >> 4;
    if (e >= N_EDGES) return;
    int c = tid & 15;
    int s = src[e]; int d = dst[e]; float v = val[e];
    float4 m = cur[(long)s * 16 + c];
    float* p = nxt + (long)d * 64 + c * 4;
    unsafeAtomicAdd(p + 0, v * m.x);
    unsafeAtomicAdd(p + 1, v * m.y);
    unsafeAtomicAdd(p + 2, v * m.z);
    unsafeAtomicAdd(p + 3, v * m.w);
}

__global__ void lgcn_add_zero(float4* __restrict__ acc, const float4* __restrict__ nxt,
                              float4* __restrict__ other) {
    int i = blockIdx.x * blockDim.x + threadIdx.x;
    if (i >= NODE_F4) return;
    float4 a = acc[i]; float4 n = nxt[i];
    a.x += n.x; a.y += n.y; a.z += n.z; a.w += n.w;
    acc[i] = a;
    other[i] = make_float4(0.f, 0.f, 0.f, 0.f);
}

__global__ void lgcn_final(float4* __restrict__ acc, const float4* __restrict__ nxt) {
    int i = blockIdx.x * blockDim.x + threadIdx.x;
    if (i >= NODE_F4) return;
    float4 a = acc[i]; float4 n = nxt[i];
    a.x = (a.x + n.x) * 0.25f; a.y = (a.y + n.y) * 0.25f;
    a.z = (a.z + n.z) * 0.25f; a.w = (a.w + n.w) * 0.25f;
    acc[i] = a;
}

// ---------------- launch ----------------

extern "C" void kernel_launch(void* const* d_in, const int* in_sizes, int n_in,
                              void* d_out, int out_size, void* d_ws, size_t ws_size,
                              hipStream_t stream) {
    const int*    adj_src  = (const int*)d_in[2];
    const int*    adj_dst  = (const int*)d_in[3];
    const float*  adj_vals = (const float*)d_in[4];
    float* acc = (float*)d_out;

    const int BLK = 256;
    const int grid_node  = (NODE_F4 + BLK - 1) / BLK;        // 9375
    const int grid_row16 = (N_NODES * 16 + BLK - 1) / BLK;   // 9375

    const size_t SZ_PAIRS = (size_t)N_EDGES * 8;             // 48,000,000
    const size_t SZ_P1PAD = (size_t)NBUCKETS * CAP_B * 8;    // 51,342,976
    const size_t SZ_BF    = (size_t)N_NODES * EMB * 2;       // 19,200,000
    const size_t SZ_RP    = 600320;                          // 150017 ints, padded
    const size_t SZ_B     = 4096;
    const size_t NEEDED1  = SZ_PAIRS + SZ_P1PAD + SZ_BF + SZ_RP + 2 * SZ_B;  // ~119.2 MB
    const size_t NEEDED2  = 2 * SZ_PAIRS + SZ_BF + SZ_RP + 3 * SZ_B;         // ~115.8 MB

    if (ws_size >= NEEDED1) {
        // ---- tier 1: padded buckets, no pre-count pipeline ----
        // [0,48M) pairs2 | [48M, +51.3M) pairs1_pad (e0b/e1b alias) |
        // [99.3M, +19.2M) e2b | row_ptr | gcur | boff
        char* w = (char*)d_ws;
        int2*    pairs2 = (int2*)(w);
        int2*    pairs1 = (int2*)(w + SZ_PAIRS);
        ushort4* e0b    = (ushort4*)(w + SZ_PAIRS);            // aliases pairs1
        ushort4* e1b    = (ushort4*)(w + SZ_PAIRS + SZ_BF);    // aliases pairs1
        ushort4* e2b    = (ushort4*)(w + SZ_PAIRS + SZ_P1PAD);
        int*  row_ptr= (int*)(w + SZ_PAIRS + SZ_P1PAD + SZ_BF);
        int*  gcur   = (int*)(w + SZ_PAIRS + SZ_P1PAD + SZ_BF + SZ_RP);
        int*  boff   = (int*)(w + SZ_PAIRS + SZ_P1PAD + SZ_BF + SZ_RP + SZ_B);

        k_ginit<<<(NBUCKETS + BLK - 1) / BLK, BLK, 0, stream>>>(gcur);
        k_part<<<PART_BLOCKS, BLK, 0, stream>>>(adj_src, adj_dst, adj_vals,
                                                gcur, pairs1);
        k_fill<<<1, 1024, 0, stream>>>(gcur, boff);
        k_sortA<<<NBUCKETS, 1024, 0, stream>>>(gcur, boff, pairs1, pairs2, row_ptr);

        k_init<<<grid_node, BLK, 0, stream>>>((const f4v*)d_in[5], (const f4v*)d_in[6],
                                              e0b, (f4v*)acc);
        k_spmm<<<grid_row16, BLK, 0, stream>>>(row_ptr, (const long*)pairs2, e0b, e1b);
        k_spmm<<<grid_row16, BLK, 0, stream>>>(row_ptr, (const long*)pairs2, e1b, e2b);
        k_spmm_fin<<<grid_row16, BLK, 0, stream>>>(row_ptr, (const long*)pairs2, e2b,
                                                   e1b, (float4*)acc);
    } else if (ws_size >= NEEDED2) {
        // ---- tier 2: R12 exact path ----
        char* w = (char*)d_ws;
        int2*    pairs2 = (int2*)(w);
        int*     cnt_pb = (int*)(w);                          // aliases pairs2 head
        int2*    pairs1 = (int2*)(w + SZ_PAIRS);
        ushort4* e0b    = (ushort4*)(w + SZ_PAIRS);           // aliases pairs1
        ushort4* e1b    = (ushort4*)(w + SZ_PAIRS + SZ_BF);   // aliases pairs1
        ushort4* e2b    = (ushort4*)(w + 2 * SZ_PAIRS);
        int*  row_ptr= (int*)(w + 2 * SZ_PAIRS + SZ_BF);
        int*  gcnt   = (int*)(w + 2 * SZ_PAIRS + SZ_BF + SZ_RP);
        int*  boff   = (int*)(w + 2 * SZ_PAIRS + SZ_BF + SZ_RP + SZ_B);

        k_zero<<<(NBUCKETS + BLK - 1) / BLK, BLK, 0, stream>>>(gcnt, NBUCKETS);
        k_bhist<<<PART_BLOCKS, BLK, 0, stream>>>(adj_dst, gcnt, cnt_pb);
        k_bscan<<<1, 1024, 0, stream>>>(gcnt, boff);
        k_pscan<<<NBUCKETS, PART_BLOCKS, 0, stream>>>(boff, cnt_pb);
        k_part2<<<PART_BLOCKS, BLK, 0, stream>>>(adj_src, adj_dst, adj_vals,
                                                 cnt_pb, pairs1);
        k_sort<<<NBUCKETS, 512, 0, stream>>>(boff, pairs1, pairs2, row_ptr);

        k_init<<<grid_node, BLK, 0, stream>>>((const f4v*)d_in[5], (const f4v*)d_in[6],
                                              e0b, (f4v*)acc);
        k_spmm<<<grid_row16, BLK, 0, stream>>>(row_ptr, (const long*)pairs2, e0b, e1b);
        k_spmm<<<grid_row16, BLK, 0, stream>>>(row_ptr, (const long*)pairs2, e1b, e2b);
        k_spmm_fin<<<grid_row16, BLK, 0, stream>>>(row_ptr, (const long*)pairs2, e2b,
                                                   e1b, (float4*)acc);
    } else {
        // ---- tier 3: R0 fallback ----
        const float4* user_emb = (const float4*)d_in[5];
        const float4* item_emb = (const float4*)d_in[6];
        float* ws0 = (float*)d_ws;
        float* ws1 = ws0 + (size_t)N_NODES * EMB;
        lgcn_init<<<grid_node, BLK, 0, stream>>>(user_emb, item_emb,
                                                 (float4*)ws0, (float4*)ws1, (float4*)acc);
        lgcn_scatter<<<(N_EDGES*16+BLK-1)/BLK, BLK, 0, stream>>>(adj_src, adj_dst, adj_vals,
                                                    (const float4*)ws0, ws1);
        lgcn_add_zero<<<grid_node, BLK, 0, stream>>>((float4*)acc, (const float4*)ws1, (float4*)ws0);
        lgcn_scatter<<<(N_EDGES*16+BLK-1)/BLK, BLK, 0, stream>>>(adj_src, adj_dst, adj_vals,
                                                    (const float4*)ws1, ws0);
        lgcn_add_zero<<<grid_node, BLK, 0, stream>>>((float4*)acc, (const float4*)ws0, (float4*)ws1);
        lgcn_scatter<<<(N_EDGES*16+BLK-1)/BLK, BLK, 0, stream>>>(adj_src, adj_dst, adj_vals,
                                                    (const float4*)ws0, ws1);
        lgcn_final<<<grid_node, BLK, 0, stream>>>((float4*)acc, (const float4*)ws1);
    }
}